// Round 2
// baseline (931.608 us; speedup 1.0000x reference)
//
#include <hip/hip_runtime.h>

#define HIDDEN 4096
#define HEADD  512
#define SEQ    2048
#define NBATCH 4
#define KSPLIT 4
#define KRANGE (SEQ/KSPLIT)   // 512 keys per flash block
#define KSTR   520            // padded K row stride in LDS (shorts): 2-way banks

typedef float f32x4 __attribute__((ext_vector_type(4)));
typedef short s16x8 __attribute__((ext_vector_type(8)));

__device__ __forceinline__ unsigned short f2bf(float x){
  unsigned u = __float_as_uint(x);
  u += 0x7fffu + ((u >> 16) & 1u);
  return (unsigned short)(u >> 16);
}
__device__ __forceinline__ float bf2f(unsigned short b){
  return __uint_as_float(((unsigned)b) << 16);
}
// async global->LDS, 16B/lane. LDS base wave-uniform; lane i lands at base + i*16.
__device__ __forceinline__ void gl_lds16(const unsigned short* g, unsigned short* l){
  __builtin_amdgcn_global_load_lds((const __attribute__((address_space(1))) unsigned int*)g,
                                   (__attribute__((address_space(3))) unsigned int*)l,
                                   16, 0, 0);
}

// ---------------- Kernel 1: split weights fp32 -> bf16 hi/lo ----------------
__global__ void wsplit_kernel(const float* __restrict__ Wq,
                              const float* __restrict__ Wk,
                              const float* __restrict__ Wv,
                              unsigned short* __restrict__ wqh, unsigned short* __restrict__ wql,
                              unsigned short* __restrict__ wkh, unsigned short* __restrict__ wkl,
                              unsigned short* __restrict__ wvh){
  const int n = HEADD * HIDDEN;
  for (int i = blockIdx.x * blockDim.x + threadIdx.x; i < n; i += gridDim.x * blockDim.x){
    float a = Wq[i]; unsigned short h = f2bf(a);
    wqh[i] = h; wql[i] = f2bf(a - bf2f(h));
    a = Wk[i]; h = f2bf(a);
    wkh[i] = h; wkl[i] = f2bf(a - bf2f(h));
    wvh[i] = f2bf(Wv[i]);
  }
}

// ---------------- Kernel 2: projection GEMM C[8192,512] = X[8192,4096]*W[512,4096]^T
// BK=64 via two 32-wide half-buffers. B via global_load_lds. A fp32 register-prefetched
// across the barrier; fp32->hi/lo conversion overlaps previous iter's MFMA.
template<int SPLITS, int MODE>
__global__ __launch_bounds__(512, 4)
void proj_kernel(const float* __restrict__ X,
                 const unsigned short* __restrict__ Wh,
                 const unsigned short* __restrict__ Wl,
                 unsigned short* __restrict__ Ohi,
                 unsigned short* __restrict__ Olo,
                 unsigned short* __restrict__ OvT){
  __shared__ unsigned short Ah[2][128*32];
  __shared__ unsigned short Al[(SPLITS>=3)?2*128*32:8];
  __shared__ unsigned short Bh[2][128*32];
  __shared__ unsigned short Bl[(SPLITS>=3)?2*128*32:8];

  const int tid  = threadIdx.x;
  const int lane = tid & 63, wid = tid >> 6;      // 8 waves
  const int quad = lane >> 4, l16 = lane & 15;
  const int wm = wid >> 1, wn = wid & 1;          // 4 x 2 wave grid, wave tile 32x64
  const int m0 = blockIdx.y * 128, n0 = blockIdx.x * 128;
  const int brow = lane >> 2;                      // B staging row within 16-row seg
  const int bcol = (lane & 3) << 3;                // B staging col (shorts)

  f32x4 acc[2][4];
  #pragma unroll
  for (int i = 0; i < 2; i++)
    #pragma unroll
    for (int j = 0; j < 4; j++){
      f32x4 z = {0.f, 0.f, 0.f, 0.f};
      acc[i][j] = z;
    }

  // A prefetch registers: 4 chunks of float4 per thread covering 128x64 fp32
  float4 xa[4];
  int ar[4], ahalf[4], acin[4];
  #pragma unroll
  for (int c = 0; c < 4; c++){
    int chunk = tid + c * 512;
    ar[c]    = chunk >> 4;
    int col4 = (chunk & 15) << 2;
    ahalf[c] = col4 >> 5;
    acin[c]  = col4 & 31;
    xa[c] = *(const float4*)(X + (size_t)(m0 + ar[c]) * HIDDEN + col4);
  }

  for (int k0 = 0; k0 < HIDDEN; k0 += 64){
    // ---- stage A from regs (fp32 -> hi/lo) ----
    #pragma unroll
    for (int c = 0; c < 4; c++){
      ushort4 hv;
      hv.x = f2bf(xa[c].x); hv.y = f2bf(xa[c].y); hv.z = f2bf(xa[c].z); hv.w = f2bf(xa[c].w);
      *(ushort4*)(&Ah[ahalf[c]][ar[c]*32 + acin[c]]) = hv;
      if (SPLITS >= 3){
        ushort4 lv;
        lv.x = f2bf(xa[c].x - bf2f(hv.x));
        lv.y = f2bf(xa[c].y - bf2f(hv.y));
        lv.z = f2bf(xa[c].z - bf2f(hv.z));
        lv.w = f2bf(xa[c].w - bf2f(hv.w));
        *(ushort4*)(&Al[ahalf[c]*4096 + ar[c]*32 + acin[c]]) = lv;
      }
    }
    // ---- stage B via global_load_lds: wave wid stages rows [wid*16,+16) per half ----
    #pragma unroll
    for (int h = 0; h < 2; h++){
      const unsigned short* gh = Wh + (size_t)(n0 + wid*16 + brow) * HIDDEN + k0 + h*32 + bcol;
      gl_lds16(gh, &Bh[h][wid*512]);
      if (SPLITS >= 3){
        const unsigned short* gl = Wl + (size_t)(n0 + wid*16 + brow) * HIDDEN + k0 + h*32 + bcol;
        gl_lds16(gl, &Bl[h*4096 + wid*512]);
      }
    }
    __syncthreads();
    // ---- prefetch next A (flies during MFMA) ----
    if (k0 + 64 < HIDDEN){
      #pragma unroll
      for (int c = 0; c < 4; c++){
        int col4 = ahalf[c]*32 + acin[c];
        xa[c] = *(const float4*)(X + (size_t)(m0 + ar[c]) * HIDDEN + k0 + 64 + col4);
      }
    }
    // ---- compute both halves ----
    #pragma unroll
    for (int h = 0; h < 2; h++){
      s16x8 ah[2], al[2], bh[4], bl[4];
      #pragma unroll
      for (int i = 0; i < 2; i++){
        ah[i] = *(const s16x8*)(&Ah[h][(wm*32 + i*16 + l16)*32 + quad*8]);
        if (SPLITS >= 3) al[i] = *(const s16x8*)(&Al[h*4096 + (wm*32 + i*16 + l16)*32 + quad*8]);
      }
      #pragma unroll
      for (int j = 0; j < 4; j++){
        bh[j] = *(const s16x8*)(&Bh[h][(wn*64 + j*16 + l16)*32 + quad*8]);
        if (SPLITS >= 3) bl[j] = *(const s16x8*)(&Bl[h*4096 + (wn*64 + j*16 + l16)*32 + quad*8]);
      }
      #pragma unroll
      for (int i = 0; i < 2; i++)
        #pragma unroll
        for (int j = 0; j < 4; j++){
          acc[i][j] = __builtin_amdgcn_mfma_f32_16x16x32_bf16(ah[i], bh[j], acc[i][j], 0, 0, 0);
          if (SPLITS >= 3){
            acc[i][j] = __builtin_amdgcn_mfma_f32_16x16x32_bf16(ah[i], bl[j], acc[i][j], 0, 0, 0);
            acc[i][j] = __builtin_amdgcn_mfma_f32_16x16x32_bf16(al[i], bh[j], acc[i][j], 0, 0, 0);
          }
        }
    }
    __syncthreads();
  }

  if (MODE == 0){
    #pragma unroll
    for (int i = 0; i < 2; i++)
      #pragma unroll
      for (int j = 0; j < 4; j++)
        #pragma unroll
        for (int r = 0; r < 4; r++){
          int m = m0 + wm*32 + i*16 + quad*4 + r;
          int n = n0 + wn*64 + j*16 + l16;
          float c = acc[i][j][r];
          unsigned short h = f2bf(c);
          Ohi[(size_t)m * HEADD + n] = h;
          Olo[(size_t)m * HEADD + n] = f2bf(c - bf2f(h));
        }
  } else {
    #pragma unroll
    for (int i = 0; i < 2; i++)
      #pragma unroll
      for (int j = 0; j < 4; j++){
        int mbase = m0 + wm*32 + i*16 + quad*4;
        int d = n0 + wn*64 + j*16 + l16;
        int b = mbase >> 11;
        int t = mbase & 2047;
        ushort4 vv;
        vv.x = f2bf(acc[i][j][0]);
        vv.y = f2bf(acc[i][j][1]);
        vv.z = f2bf(acc[i][j][2]);
        vv.w = f2bf(acc[i][j][3]);
        *(ushort4*)(OvT + ((size_t)(b * HEADD + d)) * SEQ + t) = vv;
      }
  }
}

// ---------------- Kernel 3: flash attention, per-wave q-ownership + K-split ----
// grid (16 q-tiles, KSPLIT, 4 batches), 512 threads = 8 waves. Wave owns 16 q rows.
// (a) XCD-aware block swizzle: the 16 q-tile blocks sharing a (b,kz) K/V slice
//     (1.5 MB) land on ONE XCD -> K/V L2-resident instead of 16x HBM re-fetch.
// (b) staging hoisted across one compute phase using ONLY __syncthreads():
//     stageK(t+1) issued right after the barrier that retires K(t) (flies under
//     softmax+PV), stageV(t+1) right after the barrier that retires V(t) (flies
//     under next QK). Same 2 barriers/tile as baseline; no inline asm.
__global__ __launch_bounds__(512, 2)
void flash_kernel(const unsigned short* __restrict__ qhh, const unsigned short* __restrict__ qhl,
                  const unsigned short* __restrict__ khh, const unsigned short* __restrict__ khl,
                  const unsigned short* __restrict__ vhT, const int* __restrict__ mask,
                  float* __restrict__ part, float* __restrict__ ml){
  __shared__ unsigned short Kh[32*KSTR];   // 33.3 KB, padded stride
  __shared__ unsigned short Kl[32*KSTR];
  __shared__ unsigned short Vt[512*32];    // 32 KB, [d][k]
  __shared__ unsigned short Pt[8*512];     // 8 KB, per-wave 16x32

  const int tid = threadIdx.x, lane = tid & 63, wid = tid >> 6;
  const int quad = lane >> 4, l16 = lane & 15;

  // XCD swizzle: dispatch id -> logical id. 256 blocks, 8 XCDs, 32 blocks/XCD.
  // XCD x serves logical blocks [32x, 32x+32) = exactly 2 full (b,kz) groups of 16.
  const int wg  = blockIdx.x + (int)gridDim.x * (blockIdx.y + (int)gridDim.y * blockIdx.z);
  const int lwg = (wg & 7) * 32 + (wg >> 3);
  const int qt = lwg & 15;
  const int kz = (lwg >> 4) & 3;
  const int b  = lwg >> 6;
  const int qrow0 = qt * 128 + wid * 16;           // wave's 16 q rows
  const int kbase = kz * KRANGE;

  // resident Q-hi fragments (64 VGPRs); Q-lo re-read from global per tile (L2-hot)
  const size_t qoff = ((size_t)(b * SEQ) + qrow0 + l16) * HEADD + quad * 8;
  s16x8 qh[16];
  #pragma unroll
  for (int ds = 0; ds < 16; ds++) qh[ds] = *(const s16x8*)(qhh + qoff + ds*32);

  float mrow[4], lrow[4];
  #pragma unroll
  for (int r = 0; r < 4; r++){ mrow[r] = -3.0e38f; lrow[r] = 0.f; }
  f32x4 oacc[32];
  #pragma unroll
  for (int j = 0; j < 32; j++){
    f32x4 z = {0.f, 0.f, 0.f, 0.f};
    oacc[j] = z;
  }

  // ---- staging helpers (8 K-loads + 4 V-loads per wave per tile) ----
  auto stageK = [&](int kt){
    #pragma unroll
    for (int c = 0; c < 4; c++){
      int keyl = wid*4 + c;
      size_t g = ((size_t)(b * SEQ) + kbase + kt + keyl) * HEADD + lane*8;
      gl_lds16(khh + g, Kh + keyl*KSTR);
      gl_lds16(khl + g, Kl + keyl*KSTR);
    }
  };
  auto stageV = [&](int kt){
    #pragma unroll
    for (int c = 0; c < 4; c++){
      int d0 = wid*64 + c*16;
      const unsigned short* vs = vhT + ((size_t)(b * HEADD) + d0 + (lane>>2)) * SEQ
                                     + kbase + kt + (lane & 3)*8;
      gl_lds16(vs, Vt + d0*32);
    }
  };

  // prologue: tile 0 fully staged and drained (syncthreads implies vmcnt(0))
  stageK(0);
  stageV(0);
  __syncthreads();

  for (int kt = 0; kt < KRANGE; kt += 32){
    const bool has_next = (kt + 32 < KRANGE);
    const int key0 = kbase + kt + l16;
    const int mk0 = mask[b * SEQ + key0];
    const int mk1 = mask[b * SEQ + key0 + 16];

    // ---- QK^T: S[16 x 32] per wave, 4-term split. V(t) loads (issued after the
    // previous barrier) are still in flight under this phase. ----
    f32x4 s0 = {0.f,0.f,0.f,0.f}, s1 = {0.f,0.f,0.f,0.f};
    #pragma unroll
    for (int ds = 0; ds < 16; ds++){
      s16x8 aL  = *(const s16x8*)(qhl + qoff + ds*32);
      s16x8 b0H = *(const s16x8*)(Kh + l16*KSTR      + ds*32 + quad*8);
      s16x8 b0L = *(const s16x8*)(Kl + l16*KSTR      + ds*32 + quad*8);
      s16x8 b1H = *(const s16x8*)(Kh + (16+l16)*KSTR + ds*32 + quad*8);
      s16x8 b1L = *(const s16x8*)(Kl + (16+l16)*KSTR + ds*32 + quad*8);
      s0 = __builtin_amdgcn_mfma_f32_16x16x32_bf16(qh[ds], b0H, s0, 0, 0, 0);
      s0 = __builtin_amdgcn_mfma_f32_16x16x32_bf16(qh[ds], b0L, s0, 0, 0, 0);
      s0 = __builtin_amdgcn_mfma_f32_16x16x32_bf16(aL,     b0H, s0, 0, 0, 0);
      s0 = __builtin_amdgcn_mfma_f32_16x16x32_bf16(aL,     b0L, s0, 0, 0, 0);
      s1 = __builtin_amdgcn_mfma_f32_16x16x32_bf16(qh[ds], b1H, s1, 0, 0, 0);
      s1 = __builtin_amdgcn_mfma_f32_16x16x32_bf16(qh[ds], b1L, s1, 0, 0, 0);
      s1 = __builtin_amdgcn_mfma_f32_16x16x32_bf16(aL,     b1H, s1, 0, 0, 0);
      s1 = __builtin_amdgcn_mfma_f32_16x16x32_bf16(aL,     b1L, s1, 0, 0, 0);
    }

    // ---- barrier 1: implicit vmcnt(0) drains V(t); all waves done reading K(t).
    // After this: V(t) resident everywhere, K buffers free for overwrite. ----
    __syncthreads();

    // ---- stage K(t+1): flies under softmax + PV, drained at barrier 2 ----
    if (has_next) stageK(kt + 32);

    // ---- scale + mask ----
    float sm0[4], sm1[4];
    #pragma unroll
    for (int r = 0; r < 4; r++){
      sm0[r] = mk0 ? s0[r] * 64.0f : -1.0e9f;
      sm1[r] = mk1 ? s1[r] * 64.0f : -1.0e9f;
    }
    // ---- wave-local online softmax (rows quad*4+r, reduce over 16 lanes) ----
    float rm[4];
    #pragma unroll
    for (int r = 0; r < 4; r++) rm[r] = fmaxf(sm0[r], sm1[r]);
    #pragma unroll
    for (int sh = 1; sh < 16; sh <<= 1){
      #pragma unroll
      for (int r = 0; r < 4; r++) rm[r] = fmaxf(rm[r], __shfl_xor(rm[r], sh, 64));
    }
    float alpha[4], p0[4], p1[4], rs[4];
    #pragma unroll
    for (int r = 0; r < 4; r++){
      float mn = fmaxf(mrow[r], rm[r]);
      alpha[r] = __expf(mrow[r] - mn);
      mrow[r] = mn;
      p0[r] = __expf(sm0[r] - mn);
      p1[r] = __expf(sm1[r] - mn);
      rs[r] = p0[r] + p1[r];
    }
    #pragma unroll
    for (int sh = 1; sh < 16; sh <<= 1){
      #pragma unroll
      for (int r = 0; r < 4; r++) rs[r] += __shfl_xor(rs[r], sh, 64);
    }
    #pragma unroll
    for (int r = 0; r < 4; r++) lrow[r] = lrow[r] * alpha[r] + rs[r];
    // ---- P -> per-wave LDS (C-layout write, A-layout read; same-wave dep only) ----
    #pragma unroll
    for (int r = 0; r < 4; r++){
      Pt[wid*512 + (quad*4 + r)*32 + l16]      = f2bf(p0[r]);
      Pt[wid*512 + (quad*4 + r)*32 + 16 + l16] = f2bf(p1[r]);
    }
    // ---- rescale O ----
    #pragma unroll
    for (int j = 0; j < 32; j++)
      #pragma unroll
      for (int r = 0; r < 4; r++) oacc[j][r] *= alpha[r];
    // ---- PV: O[16x512] += P[16x32] * V[32x512]  (V(t) resident per barrier 1) ----
    s16x8 pa = *(const s16x8*)(Pt + wid*512 + l16*32 + quad*8);
    #pragma unroll
    for (int j = 0; j < 32; j++){
      s16x8 vb = *(const s16x8*)(Vt + (j*16 + l16)*32 + quad*8);
      oacc[j] = __builtin_amdgcn_mfma_f32_16x16x32_bf16(pa, vb, oacc[j], 0, 0, 0);
    }

    // ---- barrier 2: implicit vmcnt(0) drains K(t+1); all waves done with V(t).
    // After this: K(t+1) resident, V buffer free for overwrite. ----
    __syncthreads();

    // ---- stage V(t+1): flies under next iteration's QK ----
    if (has_next) stageV(kt + 32);
  }

  // ---- write fp32 partials + (m,l) ----
  const size_t prow = (size_t)(kz * (NBATCH*SEQ)) + b * SEQ + qrow0;
  #pragma unroll
  for (int j = 0; j < 32; j++)
    #pragma unroll
    for (int r = 0; r < 4; r++)
      part[(prow + quad*4 + r) * HEADD + j*16 + l16] = oacc[j][r];
  if (l16 == 0){
    #pragma unroll
    for (int r = 0; r < 4; r++){
      ml[(prow + quad*4 + r)*2 + 0] = mrow[r];
      ml[(prow + quad*4 + r)*2 + 1] = lrow[r];
    }
  }
}

// ---------------- Kernel 4: combine KSPLIT partials ----------------
__global__ __launch_bounds__(256)
void reduce_kernel(const float* __restrict__ part, const float* __restrict__ ml,
                   float* __restrict__ out){
  const int row = blockIdx.x;            // b*SEQ + s in [0, 8192)
  const int t = threadIdx.x;
  float m[KSPLIT], l[KSPLIT];
  float M = -3.0e38f;
  #pragma unroll
  for (int j = 0; j < KSPLIT; j++){
    m[j] = ml[((size_t)j*(NBATCH*SEQ) + row)*2 + 0];
    l[j] = ml[((size_t)j*(NBATCH*SEQ) + row)*2 + 1];
    M = fmaxf(M, m[j]);
  }
  float w[KSPLIT], L = 0.f;
  #pragma unroll
  for (int j = 0; j < KSPLIT; j++){
    w[j] = __expf(m[j] - M);
    L += w[j] * l[j];
  }
  const float invL = 1.0f / L;
  #pragma unroll
  for (int c = 0; c < 2; c++){
    int d = t + c*256;
    float acc = 0.f;
    #pragma unroll
    for (int j = 0; j < KSPLIT; j++)
      acc += w[j] * part[((size_t)j*(NBATCH*SEQ) + row)*HEADD + d];
    out[(size_t)row * HEADD + d] = acc * invL;
  }
}

extern "C" void kernel_launch(void* const* d_in, const int* in_sizes, int n_in,
                              void* d_out, int out_size, void* d_ws, size_t ws_size,
                              hipStream_t stream){
  const float* q    = (const float*)d_in[0];
  const float* k    = (const float*)d_in[1];
  const float* v    = (const float*)d_in[2];
  const int*   mask = (const int*)d_in[3];
  const float* Wq   = (const float*)d_in[4];
  const float* Wk   = (const float*)d_in[5];
  const float* Wv   = (const float*)d_in[6];
  float* out = (float*)d_out;

  char* ws = (char*)d_ws;
  const size_t MB = 1024 * 1024;
  unsigned short* wqh = (unsigned short*)(ws + 0*MB);
  unsigned short* wql = (unsigned short*)(ws + 4*MB);
  unsigned short* wkh = (unsigned short*)(ws + 8*MB);
  unsigned short* wkl = (unsigned short*)(ws + 12*MB);
  unsigned short* wvh = (unsigned short*)(ws + 16*MB);
  unsigned short* qhh = (unsigned short*)(ws + 20*MB);
  unsigned short* qhl = (unsigned short*)(ws + 28*MB);
  unsigned short* khh = (unsigned short*)(ws + 36*MB);
  unsigned short* khl = (unsigned short*)(ws + 44*MB);
  unsigned short* vhT = (unsigned short*)(ws + 52*MB);
  float*          part = (float*)(ws + 60*MB);          // KSPLIT*8192*512 fp32 = 64 MB
  float*          mlb  = (float*)(ws + 124*MB);         // KSPLIT*8192*2 fp32 = 256 KB

  hipLaunchKernelGGL(wsplit_kernel, dim3(1024), dim3(256), 0, stream,
                     Wq, Wk, Wv, wqh, wql, wkh, wkl, wvh);
  hipLaunchKernelGGL((proj_kernel<3,0>), dim3(4, 64), dim3(512), 0, stream,
                     q, wqh, wql, qhh, qhl, (unsigned short*)nullptr);
  hipLaunchKernelGGL((proj_kernel<3,0>), dim3(4, 64), dim3(512), 0, stream,
                     k, wkh, wkl, khh, khl, (unsigned short*)nullptr);
  hipLaunchKernelGGL((proj_kernel<1,1>), dim3(4, 64), dim3(512), 0, stream,
                     v, wvh, wvh, (unsigned short*)nullptr, (unsigned short*)nullptr, vhT);
  hipLaunchKernelGGL(flash_kernel, dim3(SEQ/128, KSPLIT, NBATCH), dim3(512), 0, stream,
                     qhh, qhl, khh, khl, vhT, mask, part, mlb);
  hipLaunchKernelGGL(reduce_kernel, dim3(NBATCH*SEQ), dim3(256), 0, stream,
                     part, mlb, out);
}

// Round 3
// 920.396 us; speedup vs baseline: 1.0122x; 1.0122x over previous
//
#include <hip/hip_runtime.h>

#define HIDDEN 4096
#define HEADD  512
#define SEQ    2048
#define NBATCH 4
#define KSPLIT 4
#define KRANGE (SEQ/KSPLIT)   // 512 keys per flash block
#define KSTR   520            // padded K row stride in LDS (shorts): 2-way banks (free)

typedef float f32x4 __attribute__((ext_vector_type(4)));
typedef short s16x8 __attribute__((ext_vector_type(8)));

__device__ __forceinline__ unsigned short f2bf(float x){
  unsigned u = __float_as_uint(x);
  u += 0x7fffu + ((u >> 16) & 1u);
  return (unsigned short)(u >> 16);
}
__device__ __forceinline__ float bf2f(unsigned short b){
  return __uint_as_float(((unsigned)b) << 16);
}
// async global->LDS, 16B/lane. LDS base wave-uniform; lane i lands at base + i*16.
__device__ __forceinline__ void gl_lds16(const unsigned short* g, unsigned short* l){
  __builtin_amdgcn_global_load_lds((const __attribute__((address_space(1))) unsigned int*)g,
                                   (__attribute__((address_space(3))) unsigned int*)l,
                                   16, 0, 0);
}

// Superrow XOR swizzle for [rows][32-short] LDS tiles (64-B rows):
//   superrow R = row>>1 (128 B = 8 slots of 16 B), slot s = (row&1)*4 + chunk,
//   stored at s' = s ^ (R&7). Bit-identical data, quarter-wave reads become 2-way.

// ---------------- Kernel 1: split weights fp32 -> bf16 hi/lo (vectorized) ----------------
__global__ void wsplit_kernel(const float* __restrict__ Wq,
                              const float* __restrict__ Wk,
                              const float* __restrict__ Wv,
                              unsigned short* __restrict__ wqh, unsigned short* __restrict__ wql,
                              unsigned short* __restrict__ wkh, unsigned short* __restrict__ wkl,
                              unsigned short* __restrict__ wvh){
  const int n4 = HEADD * HIDDEN / 4;
  for (int i = blockIdx.x * blockDim.x + threadIdx.x; i < n4; i += gridDim.x * blockDim.x){
    float4 a = ((const float4*)Wq)[i];
    ushort4 h, lo;
    h.x = f2bf(a.x); lo.x = f2bf(a.x - bf2f(h.x));
    h.y = f2bf(a.y); lo.y = f2bf(a.y - bf2f(h.y));
    h.z = f2bf(a.z); lo.z = f2bf(a.z - bf2f(h.z));
    h.w = f2bf(a.w); lo.w = f2bf(a.w - bf2f(h.w));
    ((ushort4*)wqh)[i] = h; ((ushort4*)wql)[i] = lo;
    a = ((const float4*)Wk)[i];
    h.x = f2bf(a.x); lo.x = f2bf(a.x - bf2f(h.x));
    h.y = f2bf(a.y); lo.y = f2bf(a.y - bf2f(h.y));
    h.z = f2bf(a.z); lo.z = f2bf(a.z - bf2f(h.z));
    h.w = f2bf(a.w); lo.w = f2bf(a.w - bf2f(h.w));
    ((ushort4*)wkh)[i] = h; ((ushort4*)wkl)[i] = lo;
    a = ((const float4*)Wv)[i];
    h.x = f2bf(a.x); h.y = f2bf(a.y); h.z = f2bf(a.z); h.w = f2bf(a.w);
    ((ushort4*)wvh)[i] = h;
  }
}

// ---------------- Kernel 2: projection GEMM C[8192,512] = X[8192,4096]*W[512,4096]^T
// BK=64 via two 32-wide half-buffers. B via global_load_lds with pre-swizzled source;
// A reg-prefetched, written to LDS at swizzled address. All LDS reads conflict-free.
template<int SPLITS, int MODE>
__global__ __launch_bounds__(512, 4)
void proj_kernel(const float* __restrict__ X,
                 const unsigned short* __restrict__ Wh,
                 const unsigned short* __restrict__ Wl,
                 unsigned short* __restrict__ Ohi,
                 unsigned short* __restrict__ Olo,
                 unsigned short* __restrict__ OvT){
  __shared__ unsigned short Ah[2][128*32];
  __shared__ unsigned short Al[(SPLITS>=3)?2*128*32:8];
  __shared__ unsigned short Bh[2][128*32];
  __shared__ unsigned short Bl[(SPLITS>=3)?2*128*32:8];

  const int tid  = threadIdx.x;
  const int lane = tid & 63, wid = tid >> 6;      // 8 waves
  const int quad = lane >> 4, l16 = lane & 15;
  const int wm = wid >> 1, wn = wid & 1;          // 4 x 2 wave grid, wave tile 32x64
  const int m0 = blockIdx.y * 128, n0 = blockIdx.x * 128;

  // B staging (gl_lds16, linear dest): lane lands at slot s'=lane&7 of superrow
  // R = wid*8 + (lane>>3). Source must supply slot s = s' ^ (R&7) = (lane&7)^(lane>>3).
  const int sB    = (lane & 7) ^ (lane >> 3);
  const int browS = ((lane >> 3) << 1) + (sB >> 2);   // row within 16-row group
  const int bcolS = (sB & 3) << 3;                    // short offset within row

  // Swizzled fragment-read base (A and B): row = base + l16, chunk = quad
  //   idx = base*32 + (l16>>1)*64 + (((l16&1)*4+quad)^(l16>>1))*8
  const int fbase = ((l16 >> 1) << 6) + ((((((l16 & 1) << 2) | quad)) ^ (l16 >> 1)) << 3);

  f32x4 acc[2][4];
  #pragma unroll
  for (int i = 0; i < 2; i++)
    #pragma unroll
    for (int j = 0; j < 4; j++){
      f32x4 z = {0.f, 0.f, 0.f, 0.f};
      acc[i][j] = z;
    }

  // A prefetch registers: 4 chunks of float4 per thread covering 128x64 fp32
  float4 xa[4];
  int ar[4], ahalf[4], acin[4], aidx[4];
  #pragma unroll
  for (int c = 0; c < 4; c++){
    int chunk = tid + c * 512;
    ar[c]    = chunk >> 4;
    int col4 = (chunk & 15) << 2;
    ahalf[c] = col4 >> 5;
    acin[c]  = col4 & 31;
    // swizzled A-write index (8-B granular): R=ar>>1, s=(ar&1)*4+(acin>>3)
    int R  = ar[c] >> 1;
    int sA = (((ar[c] & 1) << 2) | (acin[c] >> 3)) ^ (R & 7);
    aidx[c] = (R << 6) + (sA << 3) + (acin[c] & 7);
    xa[c] = *(const float4*)(X + (size_t)(m0 + ar[c]) * HIDDEN + col4);
  }

  for (int k0 = 0; k0 < HIDDEN; k0 += 64){
    // ---- stage A from regs (fp32 -> hi/lo) at swizzled addresses ----
    #pragma unroll
    for (int c = 0; c < 4; c++){
      ushort4 hv;
      hv.x = f2bf(xa[c].x); hv.y = f2bf(xa[c].y); hv.z = f2bf(xa[c].z); hv.w = f2bf(xa[c].w);
      *(ushort4*)(&Ah[ahalf[c]][aidx[c]]) = hv;
      if (SPLITS >= 3){
        ushort4 lv;
        lv.x = f2bf(xa[c].x - bf2f(hv.x));
        lv.y = f2bf(xa[c].y - bf2f(hv.y));
        lv.z = f2bf(xa[c].z - bf2f(hv.z));
        lv.w = f2bf(xa[c].w - bf2f(hv.w));
        *(ushort4*)(&Al[ahalf[c]*4096 + aidx[c]]) = lv;
      }
    }
    // ---- stage B via global_load_lds (linear dest, pre-swizzled source) ----
    #pragma unroll
    for (int h = 0; h < 2; h++){
      const unsigned short* gh = Wh + (size_t)(n0 + wid*16 + browS) * HIDDEN + k0 + h*32 + bcolS;
      gl_lds16(gh, &Bh[h][wid*512]);
      if (SPLITS >= 3){
        const unsigned short* gl = Wl + (size_t)(n0 + wid*16 + browS) * HIDDEN + k0 + h*32 + bcolS;
        gl_lds16(gl, &Bl[h*4096 + wid*512]);
      }
    }
    __syncthreads();
    // ---- prefetch next A (flies during MFMA) ----
    if (k0 + 64 < HIDDEN){
      #pragma unroll
      for (int c = 0; c < 4; c++){
        int col4 = ahalf[c]*32 + acin[c];
        xa[c] = *(const float4*)(X + (size_t)(m0 + ar[c]) * HIDDEN + k0 + 64 + col4);
      }
    }
    // ---- compute both halves ----
    #pragma unroll
    for (int h = 0; h < 2; h++){
      s16x8 ah[2], al[2], bh[4], bl[4];
      #pragma unroll
      for (int i = 0; i < 2; i++){
        ah[i] = *(const s16x8*)(&Ah[h][(wm*32 + i*16)*32 + fbase]);
        if (SPLITS >= 3) al[i] = *(const s16x8*)(&Al[h*4096 + (wm*32 + i*16)*32 + fbase]);
      }
      #pragma unroll
      for (int j = 0; j < 4; j++){
        bh[j] = *(const s16x8*)(&Bh[h][(wn*64 + j*16)*32 + fbase]);
        if (SPLITS >= 3) bl[j] = *(const s16x8*)(&Bl[h*4096 + (wn*64 + j*16)*32 + fbase]);
      }
      #pragma unroll
      for (int i = 0; i < 2; i++)
        #pragma unroll
        for (int j = 0; j < 4; j++){
          acc[i][j] = __builtin_amdgcn_mfma_f32_16x16x32_bf16(ah[i], bh[j], acc[i][j], 0, 0, 0);
          if (SPLITS >= 3){
            acc[i][j] = __builtin_amdgcn_mfma_f32_16x16x32_bf16(ah[i], bl[j], acc[i][j], 0, 0, 0);
            acc[i][j] = __builtin_amdgcn_mfma_f32_16x16x32_bf16(al[i], bh[j], acc[i][j], 0, 0, 0);
          }
        }
    }
    __syncthreads();
  }

  if (MODE == 0){
    #pragma unroll
    for (int i = 0; i < 2; i++)
      #pragma unroll
      for (int j = 0; j < 4; j++)
        #pragma unroll
        for (int r = 0; r < 4; r++){
          int m = m0 + wm*32 + i*16 + quad*4 + r;
          int n = n0 + wn*64 + j*16 + l16;
          float c = acc[i][j][r];
          unsigned short h = f2bf(c);
          Ohi[(size_t)m * HEADD + n] = h;
          Olo[(size_t)m * HEADD + n] = f2bf(c - bf2f(h));
        }
  } else {
    #pragma unroll
    for (int i = 0; i < 2; i++)
      #pragma unroll
      for (int j = 0; j < 4; j++){
        int mbase = m0 + wm*32 + i*16 + quad*4;
        int d = n0 + wn*64 + j*16 + l16;
        int b = mbase >> 11;
        int t = mbase & 2047;
        ushort4 vv;
        vv.x = f2bf(acc[i][j][0]);
        vv.y = f2bf(acc[i][j][1]);
        vv.z = f2bf(acc[i][j][2]);
        vv.w = f2bf(acc[i][j][3]);
        *(ushort4*)(OvT + ((size_t)(b * HEADD + d)) * SEQ + t) = vv;
      }
  }
}

// ---------------- Kernel 3: flash attention, per-wave q-ownership + K-split ----
// grid (16 q-tiles, KSPLIT, 4 batches), 512 threads = 8 waves. Wave owns 16 q rows.
// XCD-aware swizzle (K/V slice L2-resident) + staggered staging (round 2) +
// THIS ROUND: superrow-XOR swizzle on Vt — PV's ds_read_b128 was 8-way bank
// conflicted (64-B rows, quarter-wave lanes hit 2 slots). 13.2M conflicts/dispatch.
__global__ __launch_bounds__(512, 2)
void flash_kernel(const unsigned short* __restrict__ qhh, const unsigned short* __restrict__ qhl,
                  const unsigned short* __restrict__ khh, const unsigned short* __restrict__ khl,
                  const unsigned short* __restrict__ vhT, const int* __restrict__ mask,
                  float* __restrict__ part, float* __restrict__ ml){
  __shared__ unsigned short Kh[32*KSTR];   // 33.3 KB, padded stride (2-way = free)
  __shared__ unsigned short Kl[32*KSTR];
  __shared__ unsigned short Vt[512*32];    // 32 KB, [d][k] superrow-swizzled
  __shared__ unsigned short Pt[8*512];     // 8 KB, per-wave 16x32

  const int tid = threadIdx.x, lane = tid & 63, wid = tid >> 6;
  const int quad = lane >> 4, l16 = lane & 15;

  // XCD swizzle: 256 blocks, 8 XCDs; XCD x serves 2 full (b,kz) groups of 16.
  const int wg  = blockIdx.x + (int)gridDim.x * (blockIdx.y + (int)gridDim.y * blockIdx.z);
  const int lwg = (wg & 7) * 32 + (wg >> 3);
  const int qt = lwg & 15;
  const int kz = (lwg >> 4) & 3;
  const int b  = lwg >> 6;
  const int qrow0 = qt * 128 + wid * 16;           // wave's 16 q rows
  const int kbase = kz * KRANGE;

  // V staging source swizzle (linear gl_lds16 dest): s = (lane&7)^(lane>>3)
  const int sV   = (lane & 7) ^ (lane >> 3);
  const int vdro = ((lane >> 3) << 1) + (sV >> 2);  // d-row offset within 16-group
  const int vcol = (sV & 3) << 3;                   // short offset within row
  // V read base: row = j*16+l16, chunk = quad ->
  //   idx = j*512 + (l16>>1)*64 + (((l16&1)*4+quad)^(l16>>1))*8
  const int vbase = ((l16 >> 1) << 6) + ((((((l16 & 1) << 2) | quad)) ^ (l16 >> 1)) << 3);

  // resident Q-hi fragments (64 VGPRs); Q-lo re-read from global per tile (L2-hot)
  const size_t qoff = ((size_t)(b * SEQ) + qrow0 + l16) * HEADD + quad * 8;
  s16x8 qh[16];
  #pragma unroll
  for (int ds = 0; ds < 16; ds++) qh[ds] = *(const s16x8*)(qhh + qoff + ds*32);

  float mrow[4], lrow[4];
  #pragma unroll
  for (int r = 0; r < 4; r++){ mrow[r] = -3.0e38f; lrow[r] = 0.f; }
  f32x4 oacc[32];
  #pragma unroll
  for (int j = 0; j < 32; j++){
    f32x4 z = {0.f, 0.f, 0.f, 0.f};
    oacc[j] = z;
  }

  // ---- staging helpers (8 K-loads + 4 V-loads per wave per tile) ----
  auto stageK = [&](int kt){
    #pragma unroll
    for (int c = 0; c < 4; c++){
      int keyl = wid*4 + c;
      size_t g = ((size_t)(b * SEQ) + kbase + kt + keyl) * HEADD + lane*8;
      gl_lds16(khh + g, Kh + keyl*KSTR);
      gl_lds16(khl + g, Kl + keyl*KSTR);
    }
  };
  auto stageV = [&](int kt){
    #pragma unroll
    for (int c = 0; c < 4; c++){
      int d0 = wid*64 + c*16;
      const unsigned short* vs = vhT + ((size_t)(b * HEADD) + d0 + vdro) * SEQ
                                     + kbase + kt + vcol;
      gl_lds16(vs, Vt + d0*32);
    }
  };

  // prologue: tile 0 fully staged and drained (syncthreads implies vmcnt(0))
  stageK(0);
  stageV(0);
  __syncthreads();

  for (int kt = 0; kt < KRANGE; kt += 32){
    const bool has_next = (kt + 32 < KRANGE);
    const int key0 = kbase + kt + l16;
    const int mk0 = mask[b * SEQ + key0];
    const int mk1 = mask[b * SEQ + key0 + 16];

    // ---- QK^T: S[16 x 32] per wave, 4-term split. V(t) loads still in flight. ----
    f32x4 s0 = {0.f,0.f,0.f,0.f}, s1 = {0.f,0.f,0.f,0.f};
    #pragma unroll
    for (int ds = 0; ds < 16; ds++){
      s16x8 aL  = *(const s16x8*)(qhl + qoff + ds*32);
      s16x8 b0H = *(const s16x8*)(Kh + l16*KSTR      + ds*32 + quad*8);
      s16x8 b0L = *(const s16x8*)(Kl + l16*KSTR      + ds*32 + quad*8);
      s16x8 b1H = *(const s16x8*)(Kh + (16+l16)*KSTR + ds*32 + quad*8);
      s16x8 b1L = *(const s16x8*)(Kl + (16+l16)*KSTR + ds*32 + quad*8);
      s0 = __builtin_amdgcn_mfma_f32_16x16x32_bf16(qh[ds], b0H, s0, 0, 0, 0);
      s0 = __builtin_amdgcn_mfma_f32_16x16x32_bf16(qh[ds], b0L, s0, 0, 0, 0);
      s0 = __builtin_amdgcn_mfma_f32_16x16x32_bf16(aL,     b0H, s0, 0, 0, 0);
      s0 = __builtin_amdgcn_mfma_f32_16x16x32_bf16(aL,     b0L, s0, 0, 0, 0);
      s1 = __builtin_amdgcn_mfma_f32_16x16x32_bf16(qh[ds], b1H, s1, 0, 0, 0);
      s1 = __builtin_amdgcn_mfma_f32_16x16x32_bf16(qh[ds], b1L, s1, 0, 0, 0);
      s1 = __builtin_amdgcn_mfma_f32_16x16x32_bf16(aL,     b1H, s1, 0, 0, 0);
      s1 = __builtin_amdgcn_mfma_f32_16x16x32_bf16(aL,     b1L, s1, 0, 0, 0);
    }

    // ---- barrier 1: drains V(t); all waves done reading K(t). ----
    __syncthreads();

    // ---- stage K(t+1): flies under softmax + PV, drained at barrier 2 ----
    if (has_next) stageK(kt + 32);

    // ---- scale + mask ----
    float sm0[4], sm1[4];
    #pragma unroll
    for (int r = 0; r < 4; r++){
      sm0[r] = mk0 ? s0[r] * 64.0f : -1.0e9f;
      sm1[r] = mk1 ? s1[r] * 64.0f : -1.0e9f;
    }
    // ---- wave-local online softmax (rows quad*4+r, reduce over 16 lanes) ----
    float rm[4];
    #pragma unroll
    for (int r = 0; r < 4; r++) rm[r] = fmaxf(sm0[r], sm1[r]);
    #pragma unroll
    for (int sh = 1; sh < 16; sh <<= 1){
      #pragma unroll
      for (int r = 0; r < 4; r++) rm[r] = fmaxf(rm[r], __shfl_xor(rm[r], sh, 64));
    }
    float alpha[4], p0[4], p1[4], rs[4];
    #pragma unroll
    for (int r = 0; r < 4; r++){
      float mn = fmaxf(mrow[r], rm[r]);
      alpha[r] = __expf(mrow[r] - mn);
      mrow[r] = mn;
      p0[r] = __expf(sm0[r] - mn);
      p1[r] = __expf(sm1[r] - mn);
      rs[r] = p0[r] + p1[r];
    }
    #pragma unroll
    for (int sh = 1; sh < 16; sh <<= 1){
      #pragma unroll
      for (int r = 0; r < 4; r++) rs[r] += __shfl_xor(rs[r], sh, 64);
    }
    #pragma unroll
    for (int r = 0; r < 4; r++) lrow[r] = lrow[r] * alpha[r] + rs[r];
    // ---- P -> per-wave LDS (C-layout write, A-layout read; same-wave dep only) ----
    #pragma unroll
    for (int r = 0; r < 4; r++){
      Pt[wid*512 + (quad*4 + r)*32 + l16]      = f2bf(p0[r]);
      Pt[wid*512 + (quad*4 + r)*32 + 16 + l16] = f2bf(p1[r]);
    }
    // ---- rescale O ----
    #pragma unroll
    for (int j = 0; j < 32; j++)
      #pragma unroll
      for (int r = 0; r < 4; r++) oacc[j][r] *= alpha[r];
    // ---- PV: O[16x512] += P[16x32] * V[32x512]  (swizzled Vt reads) ----
    s16x8 pa = *(const s16x8*)(Pt + wid*512 + l16*32 + quad*8);
    #pragma unroll
    for (int j = 0; j < 32; j++){
      s16x8 vb = *(const s16x8*)(Vt + j*512 + vbase);
      oacc[j] = __builtin_amdgcn_mfma_f32_16x16x32_bf16(pa, vb, oacc[j], 0, 0, 0);
    }

    // ---- barrier 2: drains K(t+1); all waves done with V(t). ----
    __syncthreads();

    // ---- stage V(t+1): flies under next iteration's QK ----
    if (has_next) stageV(kt + 32);
  }

  // ---- write fp32 partials + (m,l) ----
  const size_t prow = (size_t)(kz * (NBATCH*SEQ)) + b * SEQ + qrow0;
  #pragma unroll
  for (int j = 0; j < 32; j++)
    #pragma unroll
    for (int r = 0; r < 4; r++)
      part[(prow + quad*4 + r) * HEADD + j*16 + l16] = oacc[j][r];
  if (l16 == 0){
    #pragma unroll
    for (int r = 0; r < 4; r++){
      ml[(prow + quad*4 + r)*2 + 0] = mrow[r];
      ml[(prow + quad*4 + r)*2 + 1] = lrow[r];
    }
  }
}

// ---------------- Kernel 4: combine KSPLIT partials ----------------
__global__ __launch_bounds__(256)
void reduce_kernel(const float* __restrict__ part, const float* __restrict__ ml,
                   float* __restrict__ out){
  const int row = blockIdx.x;            // b*SEQ + s in [0, 8192)
  const int t = threadIdx.x;
  float m[KSPLIT], l[KSPLIT];
  float M = -3.0e38f;
  #pragma unroll
  for (int j = 0; j < KSPLIT; j++){
    m[j] = ml[((size_t)j*(NBATCH*SEQ) + row)*2 + 0];
    l[j] = ml[((size_t)j*(NBATCH*SEQ) + row)*2 + 1];
    M = fmaxf(M, m[j]);
  }
  float w[KSPLIT], L = 0.f;
  #pragma unroll
  for (int j = 0; j < KSPLIT; j++){
    w[j] = __expf(m[j] - M);
    L += w[j] * l[j];
  }
  const float invL = 1.0f / L;
  #pragma unroll
  for (int c = 0; c < 2; c++){
    int d = t + c*256;
    float acc = 0.f;
    #pragma unroll
    for (int j = 0; j < KSPLIT; j++)
      acc += w[j] * part[((size_t)j*(NBATCH*SEQ) + row)*HEADD + d];
    out[(size_t)row * HEADD + d] = acc * invL;
  }
}

extern "C" void kernel_launch(void* const* d_in, const int* in_sizes, int n_in,
                              void* d_out, int out_size, void* d_ws, size_t ws_size,
                              hipStream_t stream){
  const float* q    = (const float*)d_in[0];
  const float* k    = (const float*)d_in[1];
  const float* v    = (const float*)d_in[2];
  const int*   mask = (const int*)d_in[3];
  const float* Wq   = (const float*)d_in[4];
  const float* Wk   = (const float*)d_in[5];
  const float* Wv   = (const float*)d_in[6];
  float* out = (float*)d_out;

  char* ws = (char*)d_ws;
  const size_t MB = 1024 * 1024;
  unsigned short* wqh = (unsigned short*)(ws + 0*MB);
  unsigned short* wql = (unsigned short*)(ws + 4*MB);
  unsigned short* wkh = (unsigned short*)(ws + 8*MB);
  unsigned short* wkl = (unsigned short*)(ws + 12*MB);
  unsigned short* wvh = (unsigned short*)(ws + 16*MB);
  unsigned short* qhh = (unsigned short*)(ws + 20*MB);
  unsigned short* qhl = (unsigned short*)(ws + 28*MB);
  unsigned short* khh = (unsigned short*)(ws + 36*MB);
  unsigned short* khl = (unsigned short*)(ws + 44*MB);
  unsigned short* vhT = (unsigned short*)(ws + 52*MB);
  float*          part = (float*)(ws + 60*MB);          // KSPLIT*8192*512 fp32 = 64 MB
  float*          mlb  = (float*)(ws + 124*MB);         // KSPLIT*8192*2 fp32 = 256 KB

  hipLaunchKernelGGL(wsplit_kernel, dim3(1024), dim3(256), 0, stream,
                     Wq, Wk, Wv, wqh, wql, wkh, wkl, wvh);
  hipLaunchKernelGGL((proj_kernel<3,0>), dim3(4, 64), dim3(512), 0, stream,
                     q, wqh, wql, qhh, qhl, (unsigned short*)nullptr);
  hipLaunchKernelGGL((proj_kernel<3,0>), dim3(4, 64), dim3(512), 0, stream,
                     k, wkh, wkl, khh, khl, (unsigned short*)nullptr);
  hipLaunchKernelGGL((proj_kernel<1,1>), dim3(4, 64), dim3(512), 0, stream,
                     v, wvh, wvh, (unsigned short*)nullptr, (unsigned short*)nullptr, vhT);
  hipLaunchKernelGGL(flash_kernel, dim3(SEQ/128, KSPLIT, NBATCH), dim3(512), 0, stream,
                     qhh, qhl, khh, khl, vhT, mask, part, mlb);
  hipLaunchKernelGGL(reduce_kernel, dim3(NBATCH*SEQ), dim3(256), 0, stream,
                     part, mlb, out);
}

// Round 4
// 839.236 us; speedup vs baseline: 1.1101x; 1.0967x over previous
//
#include <hip/hip_runtime.h>

#define HIDDEN 4096
#define HEADD  512
#define SEQ    2048
#define NBATCH 4
#define KSPLIT 4
#define KRANGE (SEQ/KSPLIT)   // 512 keys per flash block
#define KSTR   520            // padded K row stride in LDS (shorts): 2-way banks (free)

typedef float f32x4 __attribute__((ext_vector_type(4)));
typedef short s16x8 __attribute__((ext_vector_type(8)));

__device__ __forceinline__ unsigned short f2bf(float x){
  unsigned u = __float_as_uint(x);
  u += 0x7fffu + ((u >> 16) & 1u);
  return (unsigned short)(u >> 16);
}
__device__ __forceinline__ float bf2f(unsigned short b){
  return __uint_as_float(((unsigned)b) << 16);
}
// async global->LDS, 16B/lane. LDS base wave-uniform; lane i lands at base + i*16.
__device__ __forceinline__ void gl_lds16(const unsigned short* g, unsigned short* l){
  __builtin_amdgcn_global_load_lds((const __attribute__((address_space(1))) unsigned int*)g,
                                   (__attribute__((address_space(3))) unsigned int*)l,
                                   16, 0, 0);
}

// ---------------- Kernel 1: split weights fp32 -> bf16 hi/lo (vectorized) ----------------
__global__ void wsplit_kernel(const float* __restrict__ Wq,
                              const float* __restrict__ Wk,
                              const float* __restrict__ Wv,
                              unsigned short* __restrict__ wqh, unsigned short* __restrict__ wql,
                              unsigned short* __restrict__ wkh, unsigned short* __restrict__ wkl,
                              unsigned short* __restrict__ wvh){
  const int n4 = HEADD * HIDDEN / 4;
  for (int i = blockIdx.x * blockDim.x + threadIdx.x; i < n4; i += gridDim.x * blockDim.x){
    float4 a = ((const float4*)Wq)[i];
    ushort4 h, lo;
    h.x = f2bf(a.x); lo.x = f2bf(a.x - bf2f(h.x));
    h.y = f2bf(a.y); lo.y = f2bf(a.y - bf2f(h.y));
    h.z = f2bf(a.z); lo.z = f2bf(a.z - bf2f(h.z));
    h.w = f2bf(a.w); lo.w = f2bf(a.w - bf2f(h.w));
    ((ushort4*)wqh)[i] = h; ((ushort4*)wql)[i] = lo;
    a = ((const float4*)Wk)[i];
    h.x = f2bf(a.x); lo.x = f2bf(a.x - bf2f(h.x));
    h.y = f2bf(a.y); lo.y = f2bf(a.y - bf2f(h.y));
    h.z = f2bf(a.z); lo.z = f2bf(a.z - bf2f(h.z));
    h.w = f2bf(a.w); lo.w = f2bf(a.w - bf2f(h.w));
    ((ushort4*)wkh)[i] = h; ((ushort4*)wkl)[i] = lo;
    a = ((const float4*)Wv)[i];
    h.x = f2bf(a.x); h.y = f2bf(a.y); h.z = f2bf(a.z); h.w = f2bf(a.w);
    ((ushort4*)wvh)[i] = h;
  }
}

// ---------------- Kernel 2: MERGED projection GEMMs (Q, K, V in one dispatch) ----
// 768 blocks (z=3 logical slices of 256): fills the 2-blocks/CU LDS capacity on all
// 256 CUs (separate 256-block launches ran at 1 block/CU = half residency).
// XCD swizzle: the 4 n-blocks sharing an X m-tile (2 MB) colocate per XCD.
// Per-slice behavior (block-uniform runtime branches):
//   z=0: X=q, W=wq (hi/lo, 3-term) -> qhh/qhl     z=1: k -> khh/khl
//   z=2: X=v, W=wv (1-term)        -> vhT (transposed [d][t] bf16)
__global__ __launch_bounds__(512, 4)
void proj_all_kernel(const float* __restrict__ q, const float* __restrict__ k,
                     const float* __restrict__ v,
                     const unsigned short* __restrict__ wqh, const unsigned short* __restrict__ wql,
                     const unsigned short* __restrict__ wkh, const unsigned short* __restrict__ wkl,
                     const unsigned short* __restrict__ wvh,
                     unsigned short* __restrict__ qhh, unsigned short* __restrict__ qhl,
                     unsigned short* __restrict__ khh, unsigned short* __restrict__ khl,
                     unsigned short* __restrict__ vhT){
  __shared__ unsigned short Ah[2][128*32];
  __shared__ unsigned short Al[2*128*32];
  __shared__ unsigned short Bh[2][128*32];
  __shared__ unsigned short Bl[2*128*32];

  const int tid  = threadIdx.x;
  const int lane = tid & 63, wid = tid >> 6;      // 8 waves
  const int quad = lane >> 4, l16 = lane & 15;
  const int wm = wid >> 1, wn = wid & 1;          // 4 x 2 wave grid, wave tile 32x64

  // XCD swizzle over 768 blocks: lwg = (wg%8)*96 + wg/8 (bijective, 768 = 8*96).
  // XCD x serves logical [96x, 96x+96): contiguous runs of complete 4-n-block groups.
  const int wg  = blockIdx.x + 4 * blockIdx.y + 256 * blockIdx.z;
  const int lwg = (wg & 7) * 96 + (wg >> 3);
  const int n0 = (lwg & 3) * 128;
  const int m0 = ((lwg >> 2) & 63) * 128;
  const int z  = lwg >> 8;

  const float* X = (z == 0) ? q : (z == 1) ? k : v;
  const unsigned short* Wh = (z == 0) ? wqh : (z == 1) ? wkh : wvh;
  const unsigned short* Wl = (z == 0) ? wql : (z == 1) ? wkl : wvh;
  unsigned short* Ohi = (z == 0) ? qhh : khh;
  unsigned short* Olo = (z == 0) ? qhl : khl;
  const bool full = (z < 2);   // 3-term hi/lo split for Q,K; single-term for V

  // B staging (gl_lds16, linear dest): lane lands at slot s'=lane&7 of superrow
  // R = wid*8 + (lane>>3). Source supplies slot s = s' ^ (R&7) = (lane&7)^(lane>>3).
  const int sB    = (lane & 7) ^ (lane >> 3);
  const int browS = ((lane >> 3) << 1) + (sB >> 2);   // row within 16-row group
  const int bcolS = (sB & 3) << 3;                    // short offset within row

  // Swizzled fragment-read base: row = base + l16, chunk = quad
  const int fbase = ((l16 >> 1) << 6) + ((((((l16 & 1) << 2) | quad)) ^ (l16 >> 1)) << 3);

  f32x4 acc[2][4];
  #pragma unroll
  for (int i = 0; i < 2; i++)
    #pragma unroll
    for (int j = 0; j < 4; j++){
      f32x4 zz = {0.f, 0.f, 0.f, 0.f};
      acc[i][j] = zz;
    }

  // A prefetch registers: 4 chunks of float4 per thread covering 128x64 fp32
  float4 xa[4];
  int ar[4], ahalf[4], acin[4], aidx[4];
  #pragma unroll
  for (int c = 0; c < 4; c++){
    int chunk = tid + c * 512;
    ar[c]    = chunk >> 4;
    int col4 = (chunk & 15) << 2;
    ahalf[c] = col4 >> 5;
    acin[c]  = col4 & 31;
    int R  = ar[c] >> 1;
    int sA = (((ar[c] & 1) << 2) | (acin[c] >> 3)) ^ (R & 7);
    aidx[c] = (R << 6) + (sA << 3) + (acin[c] & 7);
    xa[c] = *(const float4*)(X + (size_t)(m0 + ar[c]) * HIDDEN + col4);
  }

  for (int k0 = 0; k0 < HIDDEN; k0 += 64){
    // ---- stage A from regs (fp32 -> hi/lo) at swizzled addresses ----
    #pragma unroll
    for (int c = 0; c < 4; c++){
      ushort4 hv;
      hv.x = f2bf(xa[c].x); hv.y = f2bf(xa[c].y); hv.z = f2bf(xa[c].z); hv.w = f2bf(xa[c].w);
      *(ushort4*)(&Ah[ahalf[c]][aidx[c]]) = hv;
      if (full){
        ushort4 lv;
        lv.x = f2bf(xa[c].x - bf2f(hv.x));
        lv.y = f2bf(xa[c].y - bf2f(hv.y));
        lv.z = f2bf(xa[c].z - bf2f(hv.z));
        lv.w = f2bf(xa[c].w - bf2f(hv.w));
        *(ushort4*)(&Al[ahalf[c]*4096 + aidx[c]]) = lv;
      }
    }
    // ---- stage B via global_load_lds (linear dest, pre-swizzled source) ----
    #pragma unroll
    for (int h = 0; h < 2; h++){
      const unsigned short* gh = Wh + (size_t)(n0 + wid*16 + browS) * HIDDEN + k0 + h*32 + bcolS;
      gl_lds16(gh, &Bh[h][wid*512]);
      if (full){
        const unsigned short* gl = Wl + (size_t)(n0 + wid*16 + browS) * HIDDEN + k0 + h*32 + bcolS;
        gl_lds16(gl, &Bl[h*4096 + wid*512]);
      }
    }
    __syncthreads();
    // ---- prefetch next A (flies during MFMA) ----
    if (k0 + 64 < HIDDEN){
      #pragma unroll
      for (int c = 0; c < 4; c++){
        int col4 = ahalf[c]*32 + acin[c];
        xa[c] = *(const float4*)(X + (size_t)(m0 + ar[c]) * HIDDEN + k0 + 64 + col4);
      }
    }
    // ---- compute both halves ----
    #pragma unroll
    for (int h = 0; h < 2; h++){
      s16x8 ah[2], al[2], bh[4], bl[4];
      #pragma unroll
      for (int i = 0; i < 2; i++){
        ah[i] = *(const s16x8*)(&Ah[h][(wm*32 + i*16)*32 + fbase]);
        if (full) al[i] = *(const s16x8*)(&Al[h*4096 + (wm*32 + i*16)*32 + fbase]);
      }
      #pragma unroll
      for (int j = 0; j < 4; j++){
        bh[j] = *(const s16x8*)(&Bh[h][(wn*64 + j*16)*32 + fbase]);
        if (full) bl[j] = *(const s16x8*)(&Bl[h*4096 + (wn*64 + j*16)*32 + fbase]);
      }
      #pragma unroll
      for (int i = 0; i < 2; i++)
        #pragma unroll
        for (int j = 0; j < 4; j++){
          acc[i][j] = __builtin_amdgcn_mfma_f32_16x16x32_bf16(ah[i], bh[j], acc[i][j], 0, 0, 0);
          if (full){
            acc[i][j] = __builtin_amdgcn_mfma_f32_16x16x32_bf16(ah[i], bl[j], acc[i][j], 0, 0, 0);
            acc[i][j] = __builtin_amdgcn_mfma_f32_16x16x32_bf16(al[i], bh[j], acc[i][j], 0, 0, 0);
          }
        }
    }
    __syncthreads();
  }

  if (full){
    #pragma unroll
    for (int i = 0; i < 2; i++)
      #pragma unroll
      for (int j = 0; j < 4; j++)
        #pragma unroll
        for (int r = 0; r < 4; r++){
          int m = m0 + wm*32 + i*16 + quad*4 + r;
          int n = n0 + wn*64 + j*16 + l16;
          float c = acc[i][j][r];
          unsigned short h = f2bf(c);
          Ohi[(size_t)m * HEADD + n] = h;
          Olo[(size_t)m * HEADD + n] = f2bf(c - bf2f(h));
        }
  } else {
    #pragma unroll
    for (int i = 0; i < 2; i++)
      #pragma unroll
      for (int j = 0; j < 4; j++){
        int mbase = m0 + wm*32 + i*16 + quad*4;
        int d = n0 + wn*64 + j*16 + l16;
        int b = mbase >> 11;
        int t = mbase & 2047;
        ushort4 vv;
        vv.x = f2bf(acc[i][j][0]);
        vv.y = f2bf(acc[i][j][1]);
        vv.z = f2bf(acc[i][j][2]);
        vv.w = f2bf(acc[i][j][3]);
        *(ushort4*)(vhT + ((size_t)(b * HEADD + d)) * SEQ + t) = vv;
      }
  }
}

// ---------------- Kernel 3: flash attention, per-wave q-ownership + K-split ----
// grid (16 q-tiles, KSPLIT, 4 batches), 512 threads = 8 waves. Wave owns 16 q rows.
// XCD gather + staggered staging + Vt swizzle (rounds 2-3).
// THIS ROUND: defer-max rescale skip (T13, THR=10) — when no row's tile-max
// exceeds running max + 10 (wave-uniform), keep old max and skip the 128x4
// oacc rescale pass (~384 AGPR-VALU ops). Combine algebra exact for any m.
__global__ __launch_bounds__(512, 2)
void flash_kernel(const unsigned short* __restrict__ qhh, const unsigned short* __restrict__ qhl,
                  const unsigned short* __restrict__ khh, const unsigned short* __restrict__ khl,
                  const unsigned short* __restrict__ vhT, const int* __restrict__ mask,
                  float* __restrict__ part, float* __restrict__ ml){
  __shared__ unsigned short Kh[32*KSTR];   // 33.3 KB, padded stride (2-way = free)
  __shared__ unsigned short Kl[32*KSTR];
  __shared__ unsigned short Vt[512*32];    // 32 KB, [d][k] superrow-swizzled
  __shared__ unsigned short Pt[8*512];     // 8 KB, per-wave 16x32

  const int tid = threadIdx.x, lane = tid & 63, wid = tid >> 6;
  const int quad = lane >> 4, l16 = lane & 15;

  // XCD swizzle: 256 blocks, 8 XCDs; XCD x serves 2 full (b,kz) groups of 16.
  const int wg  = blockIdx.x + (int)gridDim.x * (blockIdx.y + (int)gridDim.y * blockIdx.z);
  const int lwg = (wg & 7) * 32 + (wg >> 3);
  const int qt = lwg & 15;
  const int kz = (lwg >> 4) & 3;
  const int b  = lwg >> 6;
  const int qrow0 = qt * 128 + wid * 16;           // wave's 16 q rows
  const int kbase = kz * KRANGE;

  // V staging source swizzle (linear gl_lds16 dest): s = (lane&7)^(lane>>3)
  const int sV   = (lane & 7) ^ (lane >> 3);
  const int vdro = ((lane >> 3) << 1) + (sV >> 2);  // d-row offset within 16-group
  const int vcol = (sV & 3) << 3;                   // short offset within row
  const int vbase = ((l16 >> 1) << 6) + ((((((l16 & 1) << 2) | quad)) ^ (l16 >> 1)) << 3);

  // resident Q-hi fragments (64 VGPRs); Q-lo re-read from global per tile (L2-hot)
  const size_t qoff = ((size_t)(b * SEQ) + qrow0 + l16) * HEADD + quad * 8;
  s16x8 qh[16];
  #pragma unroll
  for (int ds = 0; ds < 16; ds++) qh[ds] = *(const s16x8*)(qhh + qoff + ds*32);

  float mrow[4], lrow[4];
  #pragma unroll
  for (int r = 0; r < 4; r++){ mrow[r] = -3.0e38f; lrow[r] = 0.f; }
  f32x4 oacc[32];
  #pragma unroll
  for (int j = 0; j < 32; j++){
    f32x4 z = {0.f, 0.f, 0.f, 0.f};
    oacc[j] = z;
  }

  // ---- staging helpers (8 K-loads + 4 V-loads per wave per tile) ----
  auto stageK = [&](int kt){
    #pragma unroll
    for (int c = 0; c < 4; c++){
      int keyl = wid*4 + c;
      size_t g = ((size_t)(b * SEQ) + kbase + kt + keyl) * HEADD + lane*8;
      gl_lds16(khh + g, Kh + keyl*KSTR);
      gl_lds16(khl + g, Kl + keyl*KSTR);
    }
  };
  auto stageV = [&](int kt){
    #pragma unroll
    for (int c = 0; c < 4; c++){
      int d0 = wid*64 + c*16;
      const unsigned short* vs = vhT + ((size_t)(b * HEADD) + d0 + vdro) * SEQ
                                     + kbase + kt + vcol;
      gl_lds16(vs, Vt + d0*32);
    }
  };

  // prologue: tile 0 fully staged and drained (syncthreads implies vmcnt(0))
  stageK(0);
  stageV(0);
  __syncthreads();

  for (int kt = 0; kt < KRANGE; kt += 32){
    const bool has_next = (kt + 32 < KRANGE);
    const int key0 = kbase + kt + l16;
    const int mk0 = mask[b * SEQ + key0];
    const int mk1 = mask[b * SEQ + key0 + 16];

    // ---- QK^T: S[16 x 32] per wave, 4-term split. V(t) loads still in flight. ----
    f32x4 s0 = {0.f,0.f,0.f,0.f}, s1 = {0.f,0.f,0.f,0.f};
    #pragma unroll
    for (int ds = 0; ds < 16; ds++){
      s16x8 aL  = *(const s16x8*)(qhl + qoff + ds*32);
      s16x8 b0H = *(const s16x8*)(Kh + l16*KSTR      + ds*32 + quad*8);
      s16x8 b0L = *(const s16x8*)(Kl + l16*KSTR      + ds*32 + quad*8);
      s16x8 b1H = *(const s16x8*)(Kh + (16+l16)*KSTR + ds*32 + quad*8);
      s16x8 b1L = *(const s16x8*)(Kl + (16+l16)*KSTR + ds*32 + quad*8);
      s0 = __builtin_amdgcn_mfma_f32_16x16x32_bf16(qh[ds], b0H, s0, 0, 0, 0);
      s0 = __builtin_amdgcn_mfma_f32_16x16x32_bf16(qh[ds], b0L, s0, 0, 0, 0);
      s0 = __builtin_amdgcn_mfma_f32_16x16x32_bf16(aL,     b0H, s0, 0, 0, 0);
      s0 = __builtin_amdgcn_mfma_f32_16x16x32_bf16(aL,     b0L, s0, 0, 0, 0);
      s1 = __builtin_amdgcn_mfma_f32_16x16x32_bf16(qh[ds], b1H, s1, 0, 0, 0);
      s1 = __builtin_amdgcn_mfma_f32_16x16x32_bf16(qh[ds], b1L, s1, 0, 0, 0);
      s1 = __builtin_amdgcn_mfma_f32_16x16x32_bf16(aL,     b1H, s1, 0, 0, 0);
      s1 = __builtin_amdgcn_mfma_f32_16x16x32_bf16(aL,     b1L, s1, 0, 0, 0);
    }

    // ---- barrier 1: drains V(t); all waves done reading K(t). ----
    __syncthreads();

    // ---- stage K(t+1): flies under softmax + PV, drained at barrier 2 ----
    if (has_next) stageK(kt + 32);

    // ---- scale + mask ----
    float sm0[4], sm1[4];
    #pragma unroll
    for (int r = 0; r < 4; r++){
      sm0[r] = mk0 ? s0[r] * 64.0f : -1.0e9f;
      sm1[r] = mk1 ? s1[r] * 64.0f : -1.0e9f;
    }
    // ---- wave-local online softmax with defer-max (rows quad*4+r) ----
    float rm[4];
    #pragma unroll
    for (int r = 0; r < 4; r++) rm[r] = fmaxf(sm0[r], sm1[r]);
    #pragma unroll
    for (int sh = 1; sh < 16; sh <<= 1){
      #pragma unroll
      for (int r = 0; r < 4; r++) rm[r] = fmaxf(rm[r], __shfl_xor(rm[r], sh, 64));
    }
    bool needv = false;
    #pragma unroll
    for (int r = 0; r < 4; r++) needv = needv || (rm[r] > mrow[r] + 10.0f);
    const bool dorescale = (__any(needv ? 1 : 0) != 0);   // wave-uniform
    float alpha[4];
    if (dorescale){
      #pragma unroll
      for (int r = 0; r < 4; r++){
        float mn = fmaxf(mrow[r], rm[r]);
        alpha[r] = __expf(mrow[r] - mn);
        mrow[r] = mn;
      }
    } else {
      #pragma unroll
      for (int r = 0; r < 4; r++) alpha[r] = 1.0f;
    }
    float p0[4], p1[4], rs[4];
    #pragma unroll
    for (int r = 0; r < 4; r++){
      p0[r] = __expf(sm0[r] - mrow[r]);
      p1[r] = __expf(sm1[r] - mrow[r]);
      rs[r] = p0[r] + p1[r];
    }
    #pragma unroll
    for (int sh = 1; sh < 16; sh <<= 1){
      #pragma unroll
      for (int r = 0; r < 4; r++) rs[r] += __shfl_xor(rs[r], sh, 64);
    }
    #pragma unroll
    for (int r = 0; r < 4; r++) lrow[r] = lrow[r] * alpha[r] + rs[r];
    // ---- P -> per-wave LDS (C-layout write, A-layout read; same-wave dep only) ----
    #pragma unroll
    for (int r = 0; r < 4; r++){
      Pt[wid*512 + (quad*4 + r)*32 + l16]      = f2bf(p0[r]);
      Pt[wid*512 + (quad*4 + r)*32 + 16 + l16] = f2bf(p1[r]);
    }
    // ---- rescale O only when the running max moved ----
    if (dorescale){
      #pragma unroll
      for (int j = 0; j < 32; j++)
        #pragma unroll
        for (int r = 0; r < 4; r++) oacc[j][r] *= alpha[r];
    }
    // ---- PV: O[16x512] += P[16x32] * V[32x512]  (swizzled Vt reads) ----
    s16x8 pa = *(const s16x8*)(Pt + wid*512 + l16*32 + quad*8);
    #pragma unroll
    for (int j = 0; j < 32; j++){
      s16x8 vb = *(const s16x8*)(Vt + j*512 + vbase);
      oacc[j] = __builtin_amdgcn_mfma_f32_16x16x32_bf16(pa, vb, oacc[j], 0, 0, 0);
    }

    // ---- barrier 2: drains K(t+1); all waves done with V(t). ----
    __syncthreads();

    // ---- stage V(t+1): flies under next iteration's QK ----
    if (has_next) stageV(kt + 32);
  }

  // ---- write fp32 partials + (m,l) ----
  const size_t prow = (size_t)(kz * (NBATCH*SEQ)) + b * SEQ + qrow0;
  #pragma unroll
  for (int j = 0; j < 32; j++)
    #pragma unroll
    for (int r = 0; r < 4; r++)
      part[(prow + quad*4 + r) * HEADD + j*16 + l16] = oacc[j][r];
  if (l16 == 0){
    #pragma unroll
    for (int r = 0; r < 4; r++){
      ml[(prow + quad*4 + r)*2 + 0] = mrow[r];
      ml[(prow + quad*4 + r)*2 + 1] = lrow[r];
    }
  }
}

// ---------------- Kernel 4: combine KSPLIT partials ----------------
__global__ __launch_bounds__(256)
void reduce_kernel(const float* __restrict__ part, const float* __restrict__ ml,
                   float* __restrict__ out){
  const int row = blockIdx.x;            // b*SEQ + s in [0, 8192)
  const int t = threadIdx.x;
  float m[KSPLIT], l[KSPLIT];
  float M = -3.0e38f;
  #pragma unroll
  for (int j = 0; j < KSPLIT; j++){
    m[j] = ml[((size_t)j*(NBATCH*SEQ) + row)*2 + 0];
    l[j] = ml[((size_t)j*(NBATCH*SEQ) + row)*2 + 1];
    M = fmaxf(M, m[j]);
  }
  float w[KSPLIT], L = 0.f;
  #pragma unroll
  for (int j = 0; j < KSPLIT; j++){
    w[j] = __expf(m[j] - M);
    L += w[j] * l[j];
  }
  const float invL = 1.0f / L;
  #pragma unroll
  for (int c = 0; c < 2; c++){
    int d = t + c*256;
    float acc = 0.f;
    #pragma unroll
    for (int j = 0; j < KSPLIT; j++)
      acc += w[j] * part[((size_t)j*(NBATCH*SEQ) + row)*HEADD + d];
    out[(size_t)row * HEADD + d] = acc * invL;
  }
}

extern "C" void kernel_launch(void* const* d_in, const int* in_sizes, int n_in,
                              void* d_out, int out_size, void* d_ws, size_t ws_size,
                              hipStream_t stream){
  const float* q    = (const float*)d_in[0];
  const float* k    = (const float*)d_in[1];
  const float* v    = (const float*)d_in[2];
  const int*   mask = (const int*)d_in[3];
  const float* Wq   = (const float*)d_in[4];
  const float* Wk   = (const float*)d_in[5];
  const float* Wv   = (const float*)d_in[6];
  float* out = (float*)d_out;

  char* ws = (char*)d_ws;
  const size_t MB = 1024 * 1024;
  unsigned short* wqh = (unsigned short*)(ws + 0*MB);
  unsigned short* wql = (unsigned short*)(ws + 4*MB);
  unsigned short* wkh = (unsigned short*)(ws + 8*MB);
  unsigned short* wkl = (unsigned short*)(ws + 12*MB);
  unsigned short* wvh = (unsigned short*)(ws + 16*MB);
  unsigned short* qhh = (unsigned short*)(ws + 20*MB);
  unsigned short* qhl = (unsigned short*)(ws + 28*MB);
  unsigned short* khh = (unsigned short*)(ws + 36*MB);
  unsigned short* khl = (unsigned short*)(ws + 44*MB);
  unsigned short* vhT = (unsigned short*)(ws + 52*MB);
  float*          part = (float*)(ws + 60*MB);          // KSPLIT*8192*512 fp32 = 64 MB
  float*          mlb  = (float*)(ws + 124*MB);         // KSPLIT*8192*2 fp32 = 256 KB

  hipLaunchKernelGGL(wsplit_kernel, dim3(1024), dim3(256), 0, stream,
                     Wq, Wk, Wv, wqh, wql, wkh, wkl, wvh);
  hipLaunchKernelGGL(proj_all_kernel, dim3(4, 64, 3), dim3(512), 0, stream,
                     q, k, v, wqh, wql, wkh, wkl, wvh, qhh, qhl, khh, khl, vhT);
  hipLaunchKernelGGL(flash_kernel, dim3(SEQ/128, KSPLIT, NBATCH), dim3(512), 0, stream,
                     qhh, qhl, khh, khl, vhT, mask, part, mlb);
  hipLaunchKernelGGL(reduce_kernel, dim3(NBATCH*SEQ), dim3(256), 0, stream,
                     part, mlb, out);
}